// Round 2
// baseline (1467.404 us; speedup 1.0000x reference)
//
#include <hip/hip_runtime.h>
#include <cstdint>
#include <cstddef>

// Problem: out[M,N] = X[M,K] * W[N,K]^T + bias,  W dequantized from 4-bit.
// M = 4*2048 = 8192, K = 4096, N = 11008.
#define Mdim 8192
#define Ndim 11008
#define Kdim 4096
#define BM 256
#define BN 256
#define BK 32
#define NK (Kdim / BK)        // 128 K-tiles
#define NBUF 4                // ring of 4 K-tile buffers (staged 3 tiles ahead)
#define TILE_ELEMS (BM * BK)  // 8192 bf16 per matrix per tile
#define GROUP_M 16            // m-tiles per scheduling group (L3 locality)

typedef __attribute__((ext_vector_type(8))) __bf16 bf16x8;   // MFMA A/B operand (4 VGPRs)
typedef __attribute__((ext_vector_type(4))) float floatx4;   // MFMA C/D operand

// round-to-nearest-even fp32 -> bf16 bits
__device__ inline unsigned f2bf(float f) {
    union { float f; unsigned u; } v; v.f = f;
    unsigned r = v.u + 0x7fffu + ((v.u >> 16) & 1u);
    return r >> 16;
}
__device__ inline unsigned pack2(float lo, float hi) {
    return f2bf(lo) | (f2bf(hi) << 16);
}

// ---- pass 1: x fp32 -> bf16. 8 elems/thread: 2x16B loads, 1x16B store ----
__global__ void cvt_x_kernel(const float4* __restrict__ x, uint4* __restrict__ o, int n8) {
    int i = blockIdx.x * blockDim.x + threadIdx.x;
    if (i >= n8) return;
    float4 a = x[2 * i];
    float4 b = x[2 * i + 1];
    uint4 r;
    r.x = pack2(a.x, a.y);
    r.y = pack2(a.z, a.w);
    r.z = pack2(b.x, b.y);
    r.w = pack2(b.z, b.w);
    o[i] = r;
}

// ---- pass 2: weight int32 -> dequantized bf16. 8 elems/thread ----
__global__ void cvt_w_kernel(const int4* __restrict__ w, uint4* __restrict__ o,
                             const float* __restrict__ scale, const float* __restrict__ zp,
                             int n8) {
    int i = blockIdx.x * blockDim.x + threadIdx.x;
    if (i >= n8) return;
    float s = scale[0];
    float z = zp[0];
    int4 a = w[2 * i];
    int4 b = w[2 * i + 1];
    uint4 r;
    r.x = pack2(((float)a.x - z) * s, ((float)a.y - z) * s);
    r.y = pack2(((float)a.z - z) * s, ((float)a.w - z) * s);
    r.z = pack2(((float)b.x - z) * s, ((float)b.y - z) * s);
    r.w = pack2(((float)b.z - z) * s, ((float)b.w - z) * s);
    o[i] = r;
}

// ---- pass 3: bf16 GEMM, 256x256 tile, deep-pipelined phased schedule ----
//
// Structure (T2+T3+T4+T5): 8 waves (2M x 4N), per-wave 128x64 output = acc[8][4].
// Ring of NBUF=4 K-tile buffers, BK=32 (A 16KB + B 16KB per tile -> 128 KiB LDS).
// Per K-tile t: 2 phases x { ds_read subtile || issue 2 global_load_lds (tile t+3)
//   -> s_barrier -> setprio(1) -> 16 MFMA -> setprio(0) -> s_barrier }.
// Counted vmcnt, never 0 in main loop:
//   - stage order is 4 loads/tile (A.h0,A.h1 at phase1; B.h0,B.h1 at phase2),
//     tile t+3 staged during tile t.
//   - at tile t end: youngest 8 loads = tiles t+2,t+3  =>  s_waitcnt vmcnt(8)
//     + s_barrier guarantees tile t+1 fully in LDS before its ds_reads.
//     (vmcnt is per-wave; each wave waits for its OWN stores, the barrier then
//     publishes all waves' LDS writes — the m201 discipline.)
//   - write-after-read safe: buf[(t+3)&3] was last ds_read at tile t-1, whose
//     trailing barrier precedes the stage issue at tile t.
//   - tail peels with vmcnt(4) -> vmcnt(0); zero outstanding at s_endpgm.
// Swizzle (conflict-free under the 8-lane/cycle b128 model, measured 0 at BK=64):
//   4 chunks (16B) per 64B row; physical chunk = logical ^ ((row>>1)&3), applied
//   on the global source side so global_load_lds dst stays linear (G21).
__global__ __launch_bounds__(512, 2) void gemm_kernel(const short* __restrict__ A,
                                                      const short* __restrict__ B,
                                                      const float* __restrict__ bias,
                                                      float* __restrict__ C) {
    __shared__ __align__(16) short As[NBUF][TILE_ELEMS];   // 64 KiB
    __shared__ __align__(16) short Bs[NBUF][TILE_ELEMS];   // 64 KiB

    const int tid   = threadIdx.x;
    const int lane  = tid & 63;
    const int wave  = tid >> 6;       // 0..7
    const int waveM = wave >> 2;      // 0..1  (2 M-waves x 4 N-waves)
    const int waveN = wave & 3;       // 0..3
    const int l15   = lane & 15;
    const int quad  = lane >> 4;

    // Grouped scheduling remap (1D grid, 43*32 = 1376 blocks).
    const int NT = Ndim / BN;                 // 43 n-tiles
    int pid   = blockIdx.x;
    if (pid >= (Ndim / BN) * (Mdim / BM)) return;   // grid guard (uniform; pre-barrier)
    int group = pid / (GROUP_M * NT);
    int rem   = pid % (GROUP_M * NT);
    int mt    = group * GROUP_M + (rem % GROUP_M);   // m fastest within group
    int nt    = rem / GROUP_M;
    const int mBase = mt * BM;
    const int nBase = nt * BN;

    floatx4 acc[8][4];
    #pragma unroll
    for (int i = 0; i < 8; ++i)
        #pragma unroll
        for (int j = 0; j < 4; ++j)
            acc[i][j] = (floatx4)0.0f;

    // Staging addresses: half-tile = 128 rows x 4 chunks (16B) = 512 chunks
    // = 1 load/thread; full tile = 2 halves (rows 0-127, 128-255).
    const int srow = tid >> 2;                  // 0..127
    const int spc  = tid & 3;                   // physical chunk col in LDS
    const int sgc  = spc ^ ((srow >> 1) & 3);   // swizzled global chunk col
    const short* gA0 = A + (size_t)(mBase + srow) * Kdim + sgc * 8;
    const short* gA1 = gA0 + (size_t)128 * Kdim;   // same swizzle: ((row+128)>>1)&3 == (row>>1)&3
    const short* gB0 = B + (size_t)(nBase + srow) * Kdim + sgc * 8;
    const short* gB1 = gB0 + (size_t)128 * Kdim;
    const int ld0 = tid * 8;          // elem offset in tile buffer (16B/thread, linear)
    const int ld1 = ld0 + 4096;       // rows 128..255

    // Compute-read offsets. rowA = waveM*128 + i*16 + l15 (no carries), so
    // (rowA>>1)&3 == (l15>>1)&3 : per-lane constant physical-chunk xor.
    const int pch  = (l15 >> 1) & 3;
    const int qa   = (quad ^ pch) * 8;
    const int aoff = (waveM * 128 + l15) * BK + qa;   // + i*512 per fragment
    const int boff = (waveN * 64  + l15) * BK + qa;   // + j*512 per fragment

#define FENCE() asm volatile("" ::: "memory")
#define BAR()   do { FENCE(); __builtin_amdgcn_s_barrier(); FENCE(); } while (0)

#define GLL(SRC, DST) __builtin_amdgcn_global_load_lds(                        \
        (const __attribute__((address_space(1))) void*)(SRC),                  \
        (__attribute__((address_space(3))) void*)(DST), 16, 0, 0)

#define STAGE_A(KT) do {                                                       \
        GLL(gA0 + (KT) * BK, &As[(KT) & 3][ld0]);                              \
        GLL(gA1 + (KT) * BK, &As[(KT) & 3][ld1]);                              \
    } while (0)
#define STAGE_B(KT) do {                                                       \
        GLL(gB0 + (KT) * BK, &Bs[(KT) & 3][ld0]);                              \
        GLL(gB1 + (KT) * BK, &Bs[(KT) & 3][ld1]);                              \
    } while (0)

#define MFMA_ROW(II, AV) do {                                                              \
        acc[II][0] = __builtin_amdgcn_mfma_f32_16x16x32_bf16(AV, b0, acc[II][0], 0, 0, 0); \
        acc[II][1] = __builtin_amdgcn_mfma_f32_16x16x32_bf16(AV, b1, acc[II][1], 0, 0, 0); \
        acc[II][2] = __builtin_amdgcn_mfma_f32_16x16x32_bf16(AV, b2, acc[II][2], 0, 0, 0); \
        acc[II][3] = __builtin_amdgcn_mfma_f32_16x16x32_bf16(AV, b3, acc[II][3], 0, 0, 0); \
    } while (0)

// One K-tile: phase1 = {reads a0-3,b0-3 | stage A(t+3) | bar | 16 MFMA | bar},
// phase2 = {reads a4-7 | stage B(t+3) | bar | 16 MFMA}; caller adds vmcnt+bar.
#define KBODY(T, DOSTAGE) do {                                                 \
        const int bi_ = (T) & 3;                                               \
        const short* ab_ = &As[bi_][aoff];                                     \
        const short* bb_ = &Bs[bi_][boff];                                     \
        bf16x8 b0 = *(const bf16x8*)(bb_ + 0 * 512);                           \
        bf16x8 b1 = *(const bf16x8*)(bb_ + 1 * 512);                           \
        bf16x8 b2 = *(const bf16x8*)(bb_ + 2 * 512);                           \
        bf16x8 b3 = *(const bf16x8*)(bb_ + 3 * 512);                           \
        bf16x8 a0 = *(const bf16x8*)(ab_ + 0 * 512);                           \
        bf16x8 a1 = *(const bf16x8*)(ab_ + 1 * 512);                           \
        bf16x8 a2 = *(const bf16x8*)(ab_ + 2 * 512);                           \
        bf16x8 a3 = *(const bf16x8*)(ab_ + 3 * 512);                           \
        if (DOSTAGE) { STAGE_A((T) + 3); }                                     \
        BAR();                                                                 \
        __builtin_amdgcn_s_setprio(1);                                         \
        MFMA_ROW(0, a0); MFMA_ROW(1, a1); MFMA_ROW(2, a2); MFMA_ROW(3, a3);    \
        __builtin_amdgcn_s_setprio(0);                                         \
        BAR();                                                                 \
        bf16x8 a4 = *(const bf16x8*)(ab_ + 4 * 512);                           \
        bf16x8 a5 = *(const bf16x8*)(ab_ + 5 * 512);                           \
        bf16x8 a6 = *(const bf16x8*)(ab_ + 6 * 512);                           \
        bf16x8 a7 = *(const bf16x8*)(ab_ + 7 * 512);                           \
        if (DOSTAGE) { STAGE_B((T) + 3); }                                     \
        BAR();                                                                 \
        __builtin_amdgcn_s_setprio(1);                                         \
        MFMA_ROW(4, a4); MFMA_ROW(5, a5); MFMA_ROW(6, a6); MFMA_ROW(7, a7);    \
        __builtin_amdgcn_s_setprio(0);                                         \
    } while (0)

    // Prologue: stage tiles 0,1,2 (12 loads); vmcnt(8) => tile 0 landed.
    STAGE_A(0); STAGE_B(0);
    STAGE_A(1); STAGE_B(1);
    STAGE_A(2); STAGE_B(2);
    asm volatile("s_waitcnt vmcnt(8)" ::: "memory");
    BAR();

    // Main loop: tile t computes from buf[t&3], stages tile t+3 into buf[(t+3)&3].
    // vmcnt(8) at tile end: youngest 8 loads = tiles t+2,t+3 => t+1 guaranteed.
    #pragma unroll 1
    for (int t = 0; t < NK - 3; ++t) {
        KBODY(t, 1);
        asm volatile("s_waitcnt vmcnt(8)" ::: "memory");
        BAR();
    }
    // Tail: no staging left; drain 8 -> 4 -> 0.
    KBODY(NK - 3, 0);
    asm volatile("s_waitcnt vmcnt(4)" ::: "memory");
    BAR();
    KBODY(NK - 2, 0);
    asm volatile("s_waitcnt vmcnt(0)" ::: "memory");
    BAR();
    KBODY(NK - 1, 0);

    // Epilogue. C/D layout (m89/m91-verified): col = lane&15, row = quad*4 + reg.
    #pragma unroll
    for (int j = 0; j < 4; ++j) {
        int col = nBase + waveN * 64 + j * 16 + l15;
        float bv = bias[col];
        #pragma unroll
        for (int i = 0; i < 8; ++i) {
            int row0 = mBase + waveM * 128 + i * 16 + quad * 4;
            #pragma unroll
            for (int r = 0; r < 4; ++r)
                C[(size_t)(row0 + r) * Ndim + col] = acc[i][j][r] + bv;
        }
    }
}

extern "C" void kernel_launch(void* const* d_in, const int* in_sizes, int n_in,
                              void* d_out, int out_size, void* d_ws, size_t ws_size,
                              hipStream_t stream) {
    const float* x     = (const float*)d_in[0];   // [4,2048,4096] fp32
    const int*   w4    = (const int*)  d_in[1];   // [11008,4096] int32, values 0..15
    const float* scale = (const float*)d_in[2];   // [1]
    const float* zp    = (const float*)d_in[3];   // [1]
    const float* bias  = (const float*)d_in[4];   // [11008]
    float* out = (float*)d_out;                   // [4,2048,11008] fp32

    // Workspace: A_bf16 [8192*4096] (67 MB) then W_bf16 [11008*4096] (90 MB).
    short* Abf = (short*)d_ws;
    short* Wbf = Abf + (size_t)Mdim * Kdim;

    const int nx8 = Mdim * Kdim / 8;              // 4194304 -> 16384 blocks
    cvt_x_kernel<<<nx8 / 256, 256, 0, stream>>>((const float4*)x, (uint4*)Abf, nx8);

    const int nw8 = Ndim * Kdim / 8;              // 5636096 -> 22016 blocks
    cvt_w_kernel<<<nw8 / 256, 256, 0, stream>>>((const int4*)w4, (uint4*)Wbf, scale, zp, nw8);

    const int nblocks = (Ndim / BN) * (Mdim / BM);  // 43*32 = 1376
    gemm_kernel<<<nblocks, 512, 0, stream>>>(Abf, Wbf, bias, out);
}

// Round 3
// 1288.375 us; speedup vs baseline: 1.1390x; 1.1390x over previous
//
#include <hip/hip_runtime.h>
#include <cstdint>
#include <cstddef>

// Problem: out[M,N] = X[M,K] * W[N,K]^T + bias,  W dequantized from 4-bit.
// M = 4*2048 = 8192, K = 4096, N = 11008.
#define Mdim 8192
#define Ndim 11008
#define Kdim 4096
#define BM 128
#define BN 128
#define BK 64
#define GROUP_M 16   // m-tiles per scheduling group (L3 locality: B fetched <=4x)

typedef __attribute__((ext_vector_type(8))) __bf16 bf16x8;   // MFMA A/B operand (4 VGPRs)
typedef __attribute__((ext_vector_type(4))) float floatx4;   // MFMA C/D operand

// round-to-nearest-even fp32 -> bf16 bits
__device__ inline unsigned f2bf(float f) {
    union { float f; unsigned u; } v; v.f = f;
    unsigned r = v.u + 0x7fffu + ((v.u >> 16) & 1u);
    return r >> 16;
}
__device__ inline unsigned pack2(float lo, float hi) {
    return f2bf(lo) | (f2bf(hi) << 16);
}

// ---- pass 1: x fp32 -> bf16. Fully coalesced: thread handles one float4 per
// iteration (16B lane-contiguous load, 8B lane-contiguous store), grid-stride.
// Old version loaded x[2i],x[2i+1] per thread = 32B lane stride = 50% per-
// instruction efficiency; this is 100% on both sides.
__global__ void cvt_x_kernel(const float4* __restrict__ x, uint2* __restrict__ o, int n4) {
    int stride = gridDim.x * blockDim.x;
    for (int i = blockIdx.x * blockDim.x + threadIdx.x; i < n4; i += stride) {
        float4 a = x[i];
        uint2 r;
        r.x = pack2(a.x, a.y);
        r.y = pack2(a.z, a.w);
        o[i] = r;
    }
}

// ---- pass 2: weight int32 -> dequantized bf16. Same coalesced structure ----
__global__ void cvt_w_kernel(const int4* __restrict__ w, uint2* __restrict__ o,
                             const float* __restrict__ scale, const float* __restrict__ zp,
                             int n4) {
    float s = scale[0];
    float z = zp[0];
    int stride = gridDim.x * blockDim.x;
    for (int i = blockIdx.x * blockDim.x + threadIdx.x; i < n4; i += stride) {
        int4 a = w[i];
        uint2 r;
        r.x = pack2(((float)a.x - z) * s, ((float)a.y - z) * s);
        r.y = pack2(((float)a.z - z) * s, ((float)a.w - z) * s);
        o[i] = r;
    }
}

// ---- pass 3: bf16 GEMM, m97-style structure + grouped block scheduling ----
// (REVERTED byte-for-byte to the measured 858 us / 861 TF version: 128x128 tile,
// BK=64, 256 threads = 4 waves, 32 KiB LDS -> ~2 blocks/CU, whose cross-block
// overlap of staging and MFMA windows (m114) is what the 256x256/128-KiB phased
// variant lost in round 2: MfmaUtil 39.2 -> 31.6, gemm 858 -> 1000 us.)
// Staging via global_load_lds width=16; LDS packed row-major [128][64] bf16 with the
// bank-conflict XOR swizzle of the 16B chunk column by (row&7) absorbed on the
// global-address side (SQ_LDS_BANK_CONFLICT == 0 measured).
// Block order: GROUP_M m-tiles iterate together, n advances every GROUP_M blocks ->
// concurrent footprint ~48 B-tiles + 16 A-tiles (~64 MB, L3-resident).
__global__ __launch_bounds__(256) void gemm_kernel(const short* __restrict__ A,
                                                   const short* __restrict__ B,
                                                   const float* __restrict__ bias,
                                                   float* __restrict__ C) {
    __shared__ __align__(16) short As[BM * BK];
    __shared__ __align__(16) short Bs[BN * BK];

    const int tid  = threadIdx.x;
    const int lane = tid & 63;
    const int wave = tid >> 6;
    const int waveM = wave >> 1;     // 2x2 wave grid
    const int waveN = wave & 1;
    const int l15  = lane & 15;
    const int quad = lane >> 4;

    // Grouped scheduling remap (1D grid, 86*64 blocks).
    const int NT = Ndim / BN;                 // 86 n-tiles
    int pid   = blockIdx.x;
    int group = pid / (GROUP_M * NT);
    int rem   = pid % (GROUP_M * NT);
    int mt    = group * GROUP_M + (rem % GROUP_M);   // m fastest within group
    int nt    = rem / GROUP_M;
    const int mBase = mt * BM;
    const int nBase = nt * BN;

    floatx4 acc[4][4];
    #pragma unroll
    for (int i = 0; i < 4; ++i)
        #pragma unroll
        for (int j = 0; j < 4; ++j)
            acc[i][j] = (floatx4)0.0f;

    // Staging addresses: tile = 128 rows x 8 chunks (16B) = 1024 chunks; 256 thr x 4.
    const short* ga[4];
    const short* gb[4];
    int ldsoff[4];
    #pragma unroll
    for (int r = 0; r < 4; ++r) {
        int li  = r * 256 + tid;     // 0..1023
        int row = li >> 3;           // 0..127
        int pc  = li & 7;            // physical chunk col in LDS
        int gc  = pc ^ (row & 7);    // swizzled global chunk col
        ga[r] = A + (size_t)(mBase + row) * Kdim + gc * 8;
        gb[r] = B + (size_t)(nBase + row) * Kdim + gc * 8;
        ldsoff[r] = li * 8;          // element offset (8 bf16 = 16 B per chunk)
    }

    for (int k0 = 0; k0 < Kdim; k0 += BK) {
        #pragma unroll
        for (int r = 0; r < 4; ++r)
            __builtin_amdgcn_global_load_lds(
                (const __attribute__((address_space(1))) void*)(ga[r] + k0),
                (__attribute__((address_space(3))) void*)(As + ldsoff[r]), 16, 0, 0);
        #pragma unroll
        for (int r = 0; r < 4; ++r)
            __builtin_amdgcn_global_load_lds(
                (const __attribute__((address_space(1))) void*)(gb[r] + k0),
                (__attribute__((address_space(3))) void*)(Bs + ldsoff[r]), 16, 0, 0);
        __syncthreads();   // drains vmcnt for the global_load_lds queue

        #pragma unroll
        for (int kk = 0; kk < 2; ++kk) {          // two k=32 MFMA steps
            bf16x8 af[4], bfr[4];
            const int c = kk * 4 + quad;          // logical chunk col for this lane
            #pragma unroll
            for (int i = 0; i < 4; ++i) {
                // A operand layout: A[m=lane&15][k=quad*8+j]
                int rowA = waveM * 64 + i * 16 + l15;
                af[i]  = *(const bf16x8*)(As + (rowA * 8 + (c ^ (rowA & 7))) * 8);
                // B operand: B[k][n=lane&15]; Bs rows are W rows (= C cols)
                int rowB = waveN * 64 + i * 16 + l15;
                bfr[i] = *(const bf16x8*)(Bs + (rowB * 8 + (c ^ (rowB & 7))) * 8);
            }
            #pragma unroll
            for (int i = 0; i < 4; ++i)
                #pragma unroll
                for (int j = 0; j < 4; ++j)
                    acc[i][j] = __builtin_amdgcn_mfma_f32_16x16x32_bf16(
                        af[i], bfr[j], acc[i][j], 0, 0, 0);
        }
        __syncthreads();   // before next iteration overwrites LDS
    }

    // Epilogue. C/D layout (m89/m91-verified): col = lane&15, row = quad*4 + reg.
    #pragma unroll
    for (int j = 0; j < 4; ++j) {
        int col = nBase + waveN * 64 + j * 16 + l15;
        float bv = bias[col];
        #pragma unroll
        for (int i = 0; i < 4; ++i) {
            int row0 = mBase + waveM * 64 + i * 16 + quad * 4;
            #pragma unroll
            for (int r = 0; r < 4; ++r)
                C[(size_t)(row0 + r) * Ndim + col] = acc[i][j][r] + bv;
        }
    }
}

extern "C" void kernel_launch(void* const* d_in, const int* in_sizes, int n_in,
                              void* d_out, int out_size, void* d_ws, size_t ws_size,
                              hipStream_t stream) {
    const float* x     = (const float*)d_in[0];   // [4,2048,4096] fp32
    const int*   w4    = (const int*)  d_in[1];   // [11008,4096] int32, values 0..15
    const float* scale = (const float*)d_in[2];   // [1]
    const float* zp    = (const float*)d_in[3];   // [1]
    const float* bias  = (const float*)d_in[4];   // [11008]
    float* out = (float*)d_out;                   // [4,2048,11008] fp32

    // Workspace: A_bf16 [8192*4096] (67 MB) then W_bf16 [11008*4096] (90 MB).
    short* Abf = (short*)d_ws;
    short* Wbf = Abf + (size_t)Mdim * Kdim;

    const int nx4 = Mdim * Kdim / 4;              // 8388608 float4-groups
    cvt_x_kernel<<<2048, 256, 0, stream>>>((const float4*)x, (uint2*)Abf, nx4);

    const int nw4 = Ndim * Kdim / 4;              // 11272192 int4-groups
    cvt_w_kernel<<<2048, 256, 0, stream>>>((const int4*)w4, (uint2*)Wbf, scale, zp, nw4);

    const int nblocks = (Ndim / BN) * (Mdim / BM);  // 86*64 = 5504
    gemm_kernel<<<nblocks, 256, 0, stream>>>(Abf, Wbf, bias, out);
}